// Round 7
// baseline (273.451 us; speedup 1.0000x reference)
//
#include <hip/hip_runtime.h>
#include <math.h>

#define B 256
#define C 1000
#define D 128
#define QN 262144

// output layout (floats):
// [0]        output        B*C      = 256000
// [256000]   output2       B*C      = 256000
// [512000]   features      (2B+Q)*D = 33619968
// [34131968] pseudo_labels (2B+Q)   = 262656
// [34394624] score_prot    B*C      = 256000
// [34650624] protos        C*D      = 128000
#define OFF_FEAT   512000
#define OFF_LBL    34131968
#define OFF_SCORE  34394624
#define OFF_PROTO  34650624

#define N_Q4   (QN * D / 4)          /* 8388608 float4: queue -> features[2B:] */
#define N_O4   (B * C / 4)           /* 64000 */
#define N_F4   (B * D / 4)           /* 8192  */
#define N_P4   (QN / 4)              /* 65536 */

#define DST_Q4   ((OFF_FEAT + 2 * B * D) / 4)
#define DST_O24  (B * C / 4)
#define DST_QF4  (OFF_FEAT / 4)
#define DST_KF4  (OFF_FEAT / 4 + N_F4)
#define DST_P4   ((OFF_LBL + 2 * B) / 4)

// small-segment ranges (float4 indices)
#define SM_O2  (N_O4)                         /* after: output2 */
#define SM_Q   (2 * N_O4)                     /* after: q       */
#define SM_K   (2 * N_O4 + N_F4)              /* after: k       */
#define SM_P   (2 * N_O4 + 2 * N_F4)          /* after: pseudo  */
#define SM_TOT (2 * N_O4 + 2 * N_F4 + N_P4)   /* 209920 float4  */

// queue copy tiling: 1024 float4 (16 KB) per tile
#define Q_TILES   (N_Q4 / 1024)               /* 8192 */
#define K1_TILES  640                         /* one-shot slice hides argmax in K1 */
#define POOL_TILES (Q_TILES - K1_TILES)       /* 7552 tiles for the dynamic pool */
#define CHUNK_T   8                           /* 8 tiles = 128 KB per atomic grab */
#define NCHUNK    (POOL_TILES / CHUNK_T)      /* 944 */

// K2 role boundaries (compute first so it dispatches earliest)
#define R_SP_END  256                         /* scoreprot: 1 row/block          */
#define R_EMA_END (R_SP_END + 250)            /* ema: 4 classes/block -> 506     */
#define SM_BLKS   ((SM_TOT + 255) / 256)      /* 820                             */
#define R_SM_END  (R_EMA_END + SM_BLKS)       /* 1326                            */
#define K2_GRID   2048                        /* 1326 role + 722 pure-pool       */

// nontemporal float4 store: HIP float4 is a class type, the builtin needs a
// native clang vector — bit-identical ext_vector_type(4) alias punches through.
typedef float f4nt __attribute__((ext_vector_type(4)));
__device__ __forceinline__ void nt_store(float4* p, float4 v) {
    __builtin_nontemporal_store(*(const f4nt*)&v, (f4nt*)p);
}

// ---------------- K1: argmax (blocks 0..B-1) + leading queue-copy slice --------
__global__ __launch_bounds__(256) void k1_kernel(
    const float* __restrict__ output,
    const float* __restrict__ partial_Y,
    const float4* __restrict__ queue,
    int* __restrict__ labels,          // d_ws: [0,256) labels, [256] pool counter
    float* __restrict__ out)
{
    const int tid = threadIdx.x;

    if (blockIdx.x >= B) {
        // one-shot queue copy tile: keep HBM busy while argmax blocks run
        const size_t base = (size_t)(blockIdx.x - B) * 1024 + tid;
        float4* __restrict__ dst = (float4*)out + DST_Q4;
        float4 a = queue[base];
        float4 b = queue[base + 256];
        float4 c = queue[base + 512];
        float4 d = queue[base + 768];
        nt_store(&dst[base],       a);
        nt_store(&dst[base + 256], b);
        nt_store(&dst[base + 512], c);
        nt_store(&dst[base + 768], d);
        return;
    }

    // block 0 also resets the K2 work-stealing counter (every launch/replay)
    if (blockIdx.x == 0 && tid == 0) labels[B] = 0;

    // argmax of output*partial_Y per row (first-occurrence ties)
    const int b = blockIdx.x;
    const float* row = output + (size_t)b * C;
    const float* msk = partial_Y + (size_t)b * C;

    float best = -INFINITY;
    int bidx = C;
    for (int c = tid; c < C; c += 256) {
        float v = row[c] * msk[c];
        if (v > best) { best = v; bidx = c; }  // strict > keeps first occurrence
    }

    __shared__ float sv[256];
    __shared__ int   si[256];
    sv[tid] = best; si[tid] = bidx;
    __syncthreads();
    for (int s = 128; s > 0; s >>= 1) {
        if (tid < s) {
            float v2 = sv[tid + s]; int i2 = si[tid + s];
            if (v2 > sv[tid] || (v2 == sv[tid] && i2 < si[tid])) {
                sv[tid] = v2; si[tid] = i2;
            }
        }
        __syncthreads();
    }
    if (tid == 0) {
        int lab = si[0];
        labels[b] = lab;
        float f = (float)lab;
        out[OFF_LBL + b]     = f;
        out[OFF_LBL + B + b] = f;
    }
}

// ---------------- K2: roles (ema/scoreprot/small) then dynamic copy pool -------
__global__ __launch_bounds__(256) void k2_kernel(
    const float* __restrict__ q,
    const float* __restrict__ kk,
    const float* __restrict__ output,
    const float* __restrict__ output2,
    const float* __restrict__ prototypes,
    const float4* __restrict__ queue,
    const float* __restrict__ queue_pseudo,
    int* __restrict__ ws,               // [0,256) labels, [256] counter
    float* __restrict__ out)
{
    const int bid = blockIdx.x;
    const int tid = threadIdx.x;

    __shared__ float logits[C];
    __shared__ float red[256];
    __shared__ float qs[D];
    __shared__ int   lab[B];
    __shared__ float ss[256];
    __shared__ int   chunk_s;

    if (bid < R_SP_END) {
        // ---- score_prot = softmax(q @ P^T), one row per block (orig protos) ---
        const int b = bid;
        if (tid < D) qs[tid] = q[(size_t)b * D + tid];
        __syncthreads();

        for (int c = tid; c < C; c += 256) {
            const float4* p4 = (const float4*)(prototypes + (size_t)c * D);
            const float4* q4 = (const float4*)qs;
            float acc = 0.f;
            #pragma unroll
            for (int d = 0; d < D / 4; ++d) {
                float4 pv = p4[d];
                float4 qv = q4[d];
                acc += pv.x * qv.x + pv.y * qv.y + pv.z * qv.z + pv.w * qv.w;
            }
            logits[c] = acc;
        }
        __syncthreads();

        float lm = -INFINITY;
        for (int c = tid; c < C; c += 256) lm = fmaxf(lm, logits[c]);
        red[tid] = lm;
        __syncthreads();
        for (int s = 128; s > 0; s >>= 1) {
            if (tid < s) red[tid] = fmaxf(red[tid], red[tid + s]);
            __syncthreads();
        }
        const float m = red[0];
        __syncthreads();

        float psum = 0.f;
        for (int c = tid; c < C; c += 256) {
            float e = expf(logits[c] - m);
            logits[c] = e;
            psum += e;
        }
        red[tid] = psum;
        __syncthreads();
        for (int s = 128; s > 0; s >>= 1) {
            if (tid < s) red[tid] += red[tid + s];
            __syncthreads();
        }
        const float denom = red[0];

        for (int c = tid; c < C; c += 256)
            out[OFF_SCORE + (size_t)b * C + c] = logits[c] / denom;
    }
    else if (bid < R_EMA_END) {
        // ---- EMA scatter + L2 normalize; 4 classes/block (2 at a time) --------
        const int ebid = bid - R_SP_END;     // 0..249
        const int half = tid >> 7;           // 0/1: which class of the pair
        const int d    = tid & 127;          // dim
        for (int i = tid; i < B; i += 256) lab[i] = ws[i];
        __syncthreads();

        #pragma unroll
        for (int kcl = 0; kcl < 2; ++kcl) {
            const int c = 4 * ebid + 2 * kcl + half;
            float val = prototypes[(size_t)c * D + d];
            #pragma unroll 8
            for (int b = 0; b < B; ++b) {
                if (lab[b] == c) {           // half-block-uniform branch
                    val = val * 0.99f + 0.01f * q[(size_t)b * D + d];
                }
            }
            ss[tid] = val * val;
            __syncthreads();
            for (int s = 64; s > 0; s >>= 1) {
                if (d < s) ss[tid] += ss[tid + s];
                __syncthreads();
            }
            float r = fmaxf(sqrtf(ss[half * 128]), 1e-12f);
            out[OFF_PROTO + (size_t)c * D + d] = val / r;
            __syncthreads();                 // ss reused next iteration
        }
    }
    else if (bid < R_SM_END) {
        // ---- small segments: output, output2, q->feat, k->feat, pseudo --------
        const size_t i = (size_t)(bid - R_EMA_END) * 256 + tid;
        float4* __restrict__ out4 = (float4*)out;
        if (i < SM_O2)       out4[i]                     = ((const float4*)output)[i];
        else if (i < SM_Q)   out4[DST_O24 + (i - SM_O2)] = ((const float4*)output2)[i - SM_O2];
        else if (i < SM_K)   out4[DST_QF4 + (i - SM_Q)]  = ((const float4*)q)[i - SM_Q];
        else if (i < SM_P)   out4[DST_KF4 + (i - SM_K)]  = ((const float4*)kk)[i - SM_K];
        else if (i < SM_TOT) out4[DST_P4 + (i - SM_P)]   = ((const float4*)queue_pseudo)[i - SM_P];
    }

    // ---- dynamic work-stealing copy pool: 128 KB chunks, 8 loads in flight ----
    float4* __restrict__ dst = (float4*)out + DST_Q4;
    int* cnt = ws + B;
    for (;;) {
        __syncthreads();                     // protect chunk_s from prior read
        if (tid == 0) chunk_s = atomicAdd(cnt, 1);
        __syncthreads();
        const int ch = chunk_s;
        if (ch >= NCHUNK) break;             // uniform exit

        const size_t base = (size_t)(K1_TILES + CHUNK_T * ch) * 1024 + tid;
        #pragma unroll
        for (int g = 0; g < 4; ++g) {
            float4 v[8];
            #pragma unroll
            for (int j = 0; j < 8; ++j)
                v[j] = queue[base + (size_t)(g * 8 + j) * 256];
            #pragma unroll
            for (int j = 0; j < 8; ++j)
                nt_store(&dst[base + (size_t)(g * 8 + j) * 256], v[j]);
        }
    }
}

extern "C" void kernel_launch(void* const* d_in, const int* in_sizes, int n_in,
                              void* d_out, int out_size, void* d_ws, size_t ws_size,
                              hipStream_t stream) {
    const float* q            = (const float*)d_in[0];
    const float* k            = (const float*)d_in[1];
    const float* output       = (const float*)d_in[2];
    const float* output2      = (const float*)d_in[3];
    const float* partial_Y    = (const float*)d_in[4];
    const float* prototypes   = (const float*)d_in[5];
    const float* queue        = (const float*)d_in[6];
    const float* queue_pseudo = (const float*)d_in[7];

    float* out = (float*)d_out;
    int* ws    = (int*)d_ws;   // [0,256) labels, [256] pool counter

    // K1: argmax (needed by ema) + small copy slice + pool-counter reset
    k1_kernel<<<B + K1_TILES, 256, 0, stream>>>(
        output, partial_Y, (const float4*)queue, ws, out);

    // K2: roles first (dispatch earliest), then all 2048 blocks drain the pool
    k2_kernel<<<K2_GRID, 256, 0, stream>>>(
        q, k, output, output2, prototypes,
        (const float4*)queue, queue_pseudo, ws, out);
}

// Round 8
// 270.738 us; speedup vs baseline: 1.0100x; 1.0100x over previous
//
#include <hip/hip_runtime.h>
#include <math.h>

#define B 256
#define C 1000
#define D 128
#define QN 262144

// output layout (floats):
// [0]        output        B*C      = 256000
// [256000]   output2       B*C      = 256000
// [512000]   features      (2B+Q)*D = 33619968
// [34131968] pseudo_labels (2B+Q)   = 262656
// [34394624] score_prot    B*C      = 256000
// [34650624] protos        C*D      = 128000
#define OFF_FEAT   512000
#define OFF_LBL    34131968
#define OFF_SCORE  34394624
#define OFF_PROTO  34650624

#define N_Q4   (QN * D / 4)          /* 8388608 float4: queue -> features[2B:] */
#define N_O4   (B * C / 4)           /* 64000 */
#define N_F4   (B * D / 4)           /* 8192  */
#define N_P4   (QN / 4)              /* 65536 */

#define DST_Q4   ((OFF_FEAT + 2 * B * D) / 4)
#define DST_O24  (B * C / 4)
#define DST_QF4  (OFF_FEAT / 4)
#define DST_KF4  (OFF_FEAT / 4 + N_F4)
#define DST_P4   ((OFF_LBL + 2 * B) / 4)

// small-segment ranges (float4 indices)
#define SM_O2  (N_O4)                         /* after: output2 */
#define SM_Q   (2 * N_O4)                     /* after: q       */
#define SM_K   (2 * N_O4 + N_F4)              /* after: k       */
#define SM_P   (2 * N_O4 + 2 * N_F4)          /* after: pseudo  */
#define SM_TOT (2 * N_O4 + 2 * N_F4 + N_P4)   /* 209920 float4  */

// queue copy split: K1 takes a leading one-shot slice; K2 grid-strides the rest
#define Q_TILES   (N_Q4 / 1024)               /* 8192 tiles of 1024 float4      */
#define K1_TILES  640                         /* one-shot slice hides argmax    */
#define POOL_BASE4 ((size_t)K1_TILES * 1024)  /* 655360                          */
#define POOL_N4    ((size_t)(Q_TILES - K1_TILES) * 1024)   /* 7733248           */

// K2 role boundaries (compute first so it dispatches earliest)
#define R_SP_END  256                         /* scoreprot: 1 row/block          */
#define R_EMA_END (R_SP_END + 250)            /* ema: 4 classes/block -> 506     */
#define SM_BLKS   ((SM_TOT + 255) / 256)      /* 820                             */
#define R_SM_END  (R_EMA_END + SM_BLKS)       /* 1326                            */
#define K2_GRID   2048
#define TOT_THR   ((size_t)K2_GRID * 256)     /* 524288 threads in grid-stride   */

// ---------------- K1: argmax (blocks 0..B-1) + leading queue-copy slice --------
__global__ __launch_bounds__(256) void k1_kernel(
    const float* __restrict__ output,
    const float* __restrict__ partial_Y,
    const float4* __restrict__ queue,
    int* __restrict__ labels,          // d_ws: [0,256) labels
    float* __restrict__ out)
{
    const int tid = threadIdx.x;

    if (blockIdx.x >= B) {
        // one-shot queue copy tile: keep HBM busy while argmax blocks run
        const size_t base = (size_t)(blockIdx.x - B) * 1024 + tid;
        float4* __restrict__ dst = (float4*)out + DST_Q4;
        float4 a = queue[base];
        float4 b = queue[base + 256];
        float4 c = queue[base + 512];
        float4 d = queue[base + 768];
        dst[base]       = a;
        dst[base + 256] = b;
        dst[base + 512] = c;
        dst[base + 768] = d;
        return;
    }

    // argmax of output*partial_Y per row (first-occurrence ties)
    const int b = blockIdx.x;
    const float* row = output + (size_t)b * C;
    const float* msk = partial_Y + (size_t)b * C;

    float best = -INFINITY;
    int bidx = C;
    for (int c = tid; c < C; c += 256) {
        float v = row[c] * msk[c];
        if (v > best) { best = v; bidx = c; }  // strict > keeps first occurrence
    }

    __shared__ float sv[256];
    __shared__ int   si[256];
    sv[tid] = best; si[tid] = bidx;
    __syncthreads();
    for (int s = 128; s > 0; s >>= 1) {
        if (tid < s) {
            float v2 = sv[tid + s]; int i2 = si[tid + s];
            if (v2 > sv[tid] || (v2 == sv[tid] && i2 < si[tid])) {
                sv[tid] = v2; si[tid] = i2;
            }
        }
        __syncthreads();
    }
    if (tid == 0) {
        int lab = si[0];
        labels[b] = lab;
        float f = (float)lab;
        out[OFF_LBL + b]     = f;
        out[OFF_LBL + B + b] = f;
    }
}

// ---------------- K2: roles (scoreprot/ema/small) then grid-stride copy --------
__global__ __launch_bounds__(256) void k2_kernel(
    const float* __restrict__ q,
    const float* __restrict__ kk,
    const float* __restrict__ output,
    const float* __restrict__ output2,
    const float* __restrict__ prototypes,
    const float4* __restrict__ queue,
    const float* __restrict__ queue_pseudo,
    const int* __restrict__ labels,     // d_ws: [0,256)
    float* __restrict__ out)
{
    const int bid = blockIdx.x;
    const int tid = threadIdx.x;

    __shared__ float logits[C];
    __shared__ float red[256];
    __shared__ float qs[D];
    __shared__ int   lab[B];
    __shared__ float ss[256];

    if (bid < R_SP_END) {
        // ---- score_prot = softmax(q @ P^T), one row per block (orig protos) ---
        const int b = bid;
        if (tid < D) qs[tid] = q[(size_t)b * D + tid];
        __syncthreads();

        for (int c = tid; c < C; c += 256) {
            const float4* p4 = (const float4*)(prototypes + (size_t)c * D);
            const float4* q4 = (const float4*)qs;
            float acc = 0.f;
            #pragma unroll
            for (int d = 0; d < D / 4; ++d) {
                float4 pv = p4[d];
                float4 qv = q4[d];
                acc += pv.x * qv.x + pv.y * qv.y + pv.z * qv.z + pv.w * qv.w;
            }
            logits[c] = acc;
        }
        __syncthreads();

        float lm = -INFINITY;
        for (int c = tid; c < C; c += 256) lm = fmaxf(lm, logits[c]);
        red[tid] = lm;
        __syncthreads();
        for (int s = 128; s > 0; s >>= 1) {
            if (tid < s) red[tid] = fmaxf(red[tid], red[tid + s]);
            __syncthreads();
        }
        const float m = red[0];
        __syncthreads();

        float psum = 0.f;
        for (int c = tid; c < C; c += 256) {
            float e = expf(logits[c] - m);
            logits[c] = e;
            psum += e;
        }
        red[tid] = psum;
        __syncthreads();
        for (int s = 128; s > 0; s >>= 1) {
            if (tid < s) red[tid] += red[tid + s];
            __syncthreads();
        }
        const float denom = red[0];

        for (int c = tid; c < C; c += 256)
            out[OFF_SCORE + (size_t)b * C + c] = logits[c] / denom;
    }
    else if (bid < R_EMA_END) {
        // ---- EMA scatter + L2 normalize; 4 classes/block (2 at a time) --------
        const int ebid = bid - R_SP_END;     // 0..249
        const int half = tid >> 7;           // 0/1: which class of the pair
        const int d    = tid & 127;          // dim
        for (int i = tid; i < B; i += 256) lab[i] = labels[i];
        __syncthreads();

        #pragma unroll
        for (int kcl = 0; kcl < 2; ++kcl) {
            const int c = 4 * ebid + 2 * kcl + half;
            float val = prototypes[(size_t)c * D + d];
            #pragma unroll 8
            for (int b = 0; b < B; ++b) {
                if (lab[b] == c) {           // half-block-uniform branch
                    val = val * 0.99f + 0.01f * q[(size_t)b * D + d];
                }
            }
            ss[tid] = val * val;
            __syncthreads();
            for (int s = 64; s > 0; s >>= 1) {
                if (d < s) ss[tid] += ss[tid + s];
                __syncthreads();
            }
            float r = fmaxf(sqrtf(ss[half * 128]), 1e-12f);
            out[OFF_PROTO + (size_t)c * D + d] = val / r;
            __syncthreads();                 // ss reused next iteration
        }
    }
    else if (bid < R_SM_END) {
        // ---- small segments: output, output2, q->feat, k->feat, pseudo --------
        const size_t i = (size_t)(bid - R_EMA_END) * 256 + tid;
        float4* __restrict__ out4 = (float4*)out;
        if (i < SM_O2)       out4[i]                     = ((const float4*)output)[i];
        else if (i < SM_Q)   out4[DST_O24 + (i - SM_O2)] = ((const float4*)output2)[i - SM_O2];
        else if (i < SM_K)   out4[DST_QF4 + (i - SM_Q)]  = ((const float4*)q)[i - SM_Q];
        else if (i < SM_P)   out4[DST_KF4 + (i - SM_K)]  = ((const float4*)kk)[i - SM_K];
        else if (i < SM_TOT) out4[DST_P4 + (i - SM_P)]   = ((const float4*)queue_pseudo)[i - SM_P];
    }

    // ---- grid-stride queue copy: device-wide sliding address window ----------
    // At any instant all waves' addresses fall in ~4 contiguous windows (one per
    // unrolled stream) — DRAM row/L3-friendly, the pattern that benches 6.3 TB/s.
    const float4* __restrict__ srcq = queue + POOL_BASE4;
    float4* __restrict__ dstq = (float4*)out + DST_Q4 + POOL_BASE4;
    const size_t gid = (size_t)bid * 256 + tid;
    size_t i = gid;
    for (; i + 3 * TOT_THR < POOL_N4; i += 4 * TOT_THR) {
        float4 a = srcq[i];
        float4 b = srcq[i +     TOT_THR];
        float4 c = srcq[i + 2 * TOT_THR];
        float4 d = srcq[i + 3 * TOT_THR];
        dstq[i]               = a;
        dstq[i +     TOT_THR] = b;
        dstq[i + 2 * TOT_THR] = c;
        dstq[i + 3 * TOT_THR] = d;
    }
    for (; i < POOL_N4; i += TOT_THR)
        dstq[i] = srcq[i];
}

extern "C" void kernel_launch(void* const* d_in, const int* in_sizes, int n_in,
                              void* d_out, int out_size, void* d_ws, size_t ws_size,
                              hipStream_t stream) {
    const float* q            = (const float*)d_in[0];
    const float* k            = (const float*)d_in[1];
    const float* output       = (const float*)d_in[2];
    const float* output2      = (const float*)d_in[3];
    const float* partial_Y    = (const float*)d_in[4];
    const float* prototypes   = (const float*)d_in[5];
    const float* queue        = (const float*)d_in[6];
    const float* queue_pseudo = (const float*)d_in[7];

    float* out  = (float*)d_out;
    int* labels = (int*)d_ws;

    // K1: argmax (needed by ema) + small copy slice to keep HBM busy
    k1_kernel<<<B + K1_TILES, 256, 0, stream>>>(
        output, partial_Y, (const float4*)queue, labels, out);

    // K2: roles first (dispatch earliest), then all blocks grid-stride the copy
    k2_kernel<<<K2_GRID, 256, 0, stream>>>(
        q, k, output, output2, prototypes,
        (const float4*)queue, queue_pseudo, labels, out);
}